// Round 4
// baseline (1606.411 us; speedup 1.0000x reference)
//
#include <hip/hip_runtime.h>
#include <hip/hip_bf16.h>
#include <cstdint>

// Problem constants: B=4, L=1024, D=1024, H=16, HD=64, FF=4096, NS=64
// Inputs: fp32 (per reference setup_inputs). Output: fp32 (reference returns float32).
#define DEVI __device__ __forceinline__

typedef __attribute__((ext_vector_type(8))) short  short8;
typedef __attribute__((ext_vector_type(8))) __bf16 bf16x8;
typedef __attribute__((ext_vector_type(4))) float  f32x4;

DEVI float bf2f(short s) {
    unsigned u = ((unsigned)(unsigned short)s) << 16;
    return __builtin_bit_cast(float, u);
}
DEVI short f2bf(float f) {
    unsigned u = __builtin_bit_cast(unsigned, f);
    u = u + 0x7FFF + ((u >> 16) & 1);   // RNE
    return (short)(u >> 16);
}

// ---------------------------------------------------- fp32 -> bf16 convert
// n must be a multiple of 2048; grid = n/2048, block = 256 (8 elems/thread)
__global__ __launch_bounds__(256) void cvt_bf16(const float* src, short* dst, long n) {
    const long i = ((long)blockIdx.x * 256 + threadIdx.x) * 8;
    const float4 a = *(const float4*)&src[i];
    const float4 b = *(const float4*)&src[i + 4];
    short8 o;
    o[0] = f2bf(a.x); o[1] = f2bf(a.y); o[2] = f2bf(a.z); o[3] = f2bf(a.w);
    o[4] = f2bf(b.x); o[5] = f2bf(b.y); o[6] = f2bf(b.z); o[7] = f2bf(b.w);
    *(short8*)&dst[i] = o;
}

// ---------------------------------------------------------------- GEMM (NT)
// C[m,n] = sum_k A[m,k] * B[n,k]  -- A,B bf16 K-contiguous, fp32 accum.
struct GArgs {
    const short* A; long lda, sAb, sAh;
    const short* B; long ldb, sBb, sBh;
    short* C;       long ldc, sCb, sCh;
    const float* bias;                       // len-N fp32, nullable
    const float* addm; long ldad, sDb, sDh;  // additive fp32 matrix (alibi), nullable
    float* resid;                            // fp32 residual, uses ldc
    float* outf;                             // EPI3 fp32 output
    const float* gate;                       // fp32 scalar, nullable
    float scale;
    int K, nh;
};

// EPI: 0: C=bf16(acc+bias)
//      1: C=bf16(acc*scale + addm)
//      2: resid += gatescale*(acc+bias)     (gatescale = scale * sigmoid(*gate))
//      3: outf = fp32(resid + acc + bias)
template<int BM, int BN, int EPI>
__global__ __launch_bounds__(256) void gemm_bt(GArgs a) {
    constexpr int WM = BM / 2, WN = BN / 2, MI = WM / 16, NI = WN / 16;
    __shared__ __align__(16) short As[BM * 32];
    __shared__ __align__(16) short Bs[BN * 32];
    const int tid = threadIdx.x;
    const int wave = tid >> 6, lane = tid & 63;
    const int wm = (wave >> 1) * WM, wn = (wave & 1) * WN;
    const int q = lane >> 4, r = lane & 15;
    const long bb = blockIdx.z / a.nh, hh = blockIdx.z % a.nh;
    const short* Ab = a.A + bb * a.sAb + hh * a.sAh + (long)blockIdx.y * BM * a.lda;
    const short* Bb = a.B + bb * a.sBb + hh * a.sBh + (long)blockIdx.x * BN * a.ldb;
    const int trow = tid >> 2;            // 4 threads/row, 8 bf16 (16B) each
    const int tcol = (tid & 3) * 8;
    f32x4 acc[MI][NI] = {};

    for (int k0 = 0; k0 < a.K; k0 += 32) {
        __syncthreads();
#pragma unroll
        for (int i = 0; i < BM / 64; i++) {
            const short* g = Ab + (long)(i * 64 + trow) * a.lda + k0 + tcol;
            __builtin_amdgcn_global_load_lds(
                (const __attribute__((address_space(1))) void*)g,
                (__attribute__((address_space(3))) void*)&As[(i * 64 + trow) * 32 + tcol],
                16, 0, 0);
        }
#pragma unroll
        for (int i = 0; i < BN / 64; i++) {
            const short* g = Bb + (long)(i * 64 + trow) * a.ldb + k0 + tcol;
            __builtin_amdgcn_global_load_lds(
                (const __attribute__((address_space(1))) void*)g,
                (__attribute__((address_space(3))) void*)&Bs[(i * 64 + trow) * 32 + tcol],
                16, 0, 0);
        }
        asm volatile("s_waitcnt vmcnt(0)" ::: "memory");
        __syncthreads();
        bf16x8 av[MI], bv[NI];
#pragma unroll
        for (int mi = 0; mi < MI; mi++)
            av[mi] = __builtin_bit_cast(bf16x8, *(const short8*)&As[(wm + mi * 16 + r) * 32 + q * 8]);
#pragma unroll
        for (int ni = 0; ni < NI; ni++)
            bv[ni] = __builtin_bit_cast(bf16x8, *(const short8*)&Bs[(wn + ni * 16 + r) * 32 + q * 8]);
#pragma unroll
        for (int mi = 0; mi < MI; mi++)
#pragma unroll
            for (int ni = 0; ni < NI; ni++)
                acc[mi][ni] = __builtin_amdgcn_mfma_f32_16x16x32_bf16(av[mi], bv[ni], acc[mi][ni], 0, 0, 0);
    }

    const long m0 = (long)blockIdx.y * BM + wm;
    const long n0 = (long)blockIdx.x * BN + wn;
    float gs = a.scale;
    if (EPI == 2 && a.gate) gs *= 1.f / (1.f + __expf(-(*a.gate)));
#pragma unroll
    for (int mi = 0; mi < MI; mi++)
#pragma unroll
        for (int ni = 0; ni < NI; ni++)
#pragma unroll
            for (int j = 0; j < 4; j++) {
                const long m = m0 + mi * 16 + q * 4 + j;   // row = quad*4+reg
                const long n = n0 + ni * 16 + r;           // col = lane&15
                float v = acc[mi][ni][j];
                if constexpr (EPI == 0) {
                    if (a.bias) v += a.bias[n];
                    a.C[bb * a.sCb + hh * a.sCh + m * a.ldc + n] = f2bf(v);
                } else if constexpr (EPI == 1) {
                    v *= a.scale;
                    if (a.addm) v += a.addm[bb * a.sDb + hh * a.sDh + m * a.ldad + n];
                    a.C[bb * a.sCb + hh * a.sCh + m * a.ldc + n] = f2bf(v);
                } else if constexpr (EPI == 2) {
                    if (a.bias) v += a.bias[n];
                    a.resid[m * a.ldc + n] += gs * v;
                } else {
                    if (a.bias) v += a.bias[n];
                    a.outf[m * a.ldc + n] = a.resid[m * a.ldc + n] + v;
                }
            }
}

// ------------------------------------------------------------- LayerNorm
// X fp32 (1024-wide rows), params fp32, output bf16
__global__ __launch_bounds__(256) void ln_rows(const float* X, const float* gw,
                                               const float* bw, short* Y) {
    const long row = blockIdx.x;
    const float* x = X + row * 1024;
    const int t = threadIdx.x;
    float v[4], s1 = 0.f, s2 = 0.f;
#pragma unroll
    for (int i = 0; i < 4; i++) {
        v[i] = x[t + i * 256];
        s1 += v[i]; s2 += v[i] * v[i];
    }
#pragma unroll
    for (int o = 32; o; o >>= 1) { s1 += __shfl_xor(s1, o); s2 += __shfl_xor(s2, o); }
    __shared__ float sm[8];
    if ((t & 63) == 0) { sm[t >> 6] = s1; sm[4 + (t >> 6)] = s2; }
    __syncthreads();
    s1 = sm[0] + sm[1] + sm[2] + sm[3];
    s2 = sm[4] + sm[5] + sm[6] + sm[7];
    const float mu = s1 * (1.f / 1024.f);
    const float var = s2 * (1.f / 1024.f) - mu * mu;
    const float rr = rsqrtf(var + 1e-5f);
#pragma unroll
    for (int i = 0; i < 4; i++) {
        const int c = t + i * 256;
        Y[row * 1024 + c] = f2bf((v[i] - mu) * rr * gw[c] + bw[c]);
    }
}

// ------------------------------------------------------------- Softmax
__global__ __launch_bounds__(256) void softmax1024(short* S) {
    const long row = blockIdx.x;
    short* p = S + row * 1024;
    const int t = threadIdx.x;
    float v[4];
#pragma unroll
    for (int i = 0; i < 4; i++) v[i] = bf2f(p[t + i * 256]);
    float m = fmaxf(fmaxf(v[0], v[1]), fmaxf(v[2], v[3]));
#pragma unroll
    for (int o = 32; o; o >>= 1) m = fmaxf(m, __shfl_xor(m, o));
    __shared__ float sm[4];
    if ((t & 63) == 0) sm[t >> 6] = m;
    __syncthreads();
    m = fmaxf(fmaxf(sm[0], sm[1]), fmaxf(sm[2], sm[3]));
    float e[4], s = 0.f;
#pragma unroll
    for (int i = 0; i < 4; i++) { e[i] = __expf(v[i] - m); s += e[i]; }
#pragma unroll
    for (int o = 32; o; o >>= 1) s += __shfl_xor(s, o);
    __syncthreads();
    if ((t & 63) == 0) sm[t >> 6] = s;
    __syncthreads();
    s = sm[0] + sm[1] + sm[2] + sm[3];
    const float inv = 1.f / s;
#pragma unroll
    for (int i = 0; i < 4; i++) p[t + i * 256] = f2bf(e[i] * inv);
}

__global__ __launch_bounds__(256) void softmax64(short* S) {
    const long row = (long)blockIdx.x * 4 + (threadIdx.x >> 6);
    const int lane = threadIdx.x & 63;
    short* p = S + row * 64;
    float v = bf2f(p[lane]);
    float m = v;
#pragma unroll
    for (int o = 32; o; o >>= 1) m = fmaxf(m, __shfl_xor(m, o));
    float e = __expf(v - m), s = e;
#pragma unroll
    for (int o = 32; o; o >>= 1) s += __shfl_xor(s, o);
    p[lane] = f2bf(e / s);
}

// ----------------------------------------------------- V transposes (per head)
__global__ __launch_bounds__(256) void transpose_v_sa(const short* qkv, short* vt) {
    // grid (16 jtiles, 16 h, 4 b): vt[(b*16+h)*64+hd][j(1024)] = v[b, j, h, hd]
    __shared__ short tbuf[64][68];
    const int j0 = blockIdx.x * 64, h = blockIdx.y, b = blockIdx.z;
    const int tid = threadIdx.x;
#pragma unroll
    for (int i = 0; i < 16; i++) {
        const int idx = i * 256 + tid, jj = idx >> 6, hd = idx & 63;
        tbuf[jj][hd] = qkv[(long)(b * 1024 + j0 + jj) * 3072 + 2048 + h * 64 + hd];
    }
    __syncthreads();
    const long bh = b * 16 + h;
#pragma unroll
    for (int i = 0; i < 16; i++) {
        const int idx = i * 256 + tid, hd = idx >> 6, jj = idx & 63;
        vt[(bh * 64 + hd) * 1024 + j0 + jj] = tbuf[jj][hd];
    }
}

__global__ __launch_bounds__(256) void transpose_v_ca(const short* kv2, short* vt2) {
    // grid 64 = b*16+h: vt2[bh*64+hd][j(64)] = v2[b, j, h, hd]; v2 = kv2 cols 1024..2047
    __shared__ short tbuf[64][68];
    const int bh = blockIdx.x, b = bh >> 4, h = bh & 15;
    const int tid = threadIdx.x;
#pragma unroll
    for (int i = 0; i < 16; i++) {
        const int idx = i * 256 + tid, jj = idx >> 6, hd = idx & 63;
        tbuf[jj][hd] = kv2[(long)(b * 64 + jj) * 2048 + 1024 + h * 64 + hd];
    }
    __syncthreads();
#pragma unroll
    for (int i = 0; i < 16; i++) {
        const int idx = i * 256 + tid, hd = idx >> 6, jj = idx & 63;
        vt2[((long)bh * 64 + hd) * 64 + jj] = tbuf[jj][hd];
    }
}

// ------------------------------------------------------------- elementwise
// In-place GeGLU on an f1 chunk: f1[m][j] <- f1[m][j] * gelu(f1[m][4096+j])
__global__ __launch_bounds__(256) void geglu_inplace(short* f1) {
    const long i = (long)blockIdx.x * 256 + threadIdx.x;  // 8 elems each
    const long m = i >> 9, j8 = (i & 511) * 8;
    const short8 av = *(const short8*)&f1[m * 8192 + j8];
    const short8 gv = *(const short8*)&f1[m * 8192 + 4096 + j8];
    short8 o;
#pragma unroll
    for (int jj = 0; jj < 8; jj++) {
        const float xv = bf2f(av[jj]), gg = bf2f(gv[jj]);
        const float ge = 0.5f * gg * (1.f + erff(gg * 0.7071067811865476f));
        o[jj] = f2bf(xv * ge);
    }
    *(short8*)&f1[m * 8192 + j8] = o;
}

// ---------------------------------------------------------------- launch
extern "C" void kernel_launch(void* const* d_in, const int* in_sizes, int n_in,
                              void* d_out, int out_size, void* d_ws, size_t ws_size,
                              hipStream_t stream) {
    const float* x        = (const float*)d_in[0];
    const float* alibi    = (const float*)d_in[1];
    const float* species  = (const float*)d_in[2];
    const float* n1g      = (const float*)d_in[3];
    const float* n1b      = (const float*)d_in[4];
    const float* sa_wqkv  = (const float*)d_in[5];
    const float* sa_bqkv  = (const float*)d_in[6];
    const float* sa_wo    = (const float*)d_in[7];
    const float* sa_bo    = (const float*)d_in[8];
    const float* ca_nq_g  = (const float*)d_in[9];
    const float* ca_nq_b  = (const float*)d_in[10];
    const float* ca_nkv_g = (const float*)d_in[11];
    const float* ca_nkv_b = (const float*)d_in[12];
    const float* ca_wqkv  = (const float*)d_in[13];
    const float* ca_bqkv  = (const float*)d_in[14];
    const float* ca_wo    = (const float*)d_in[15];
    const float* ca_bo    = (const float*)d_in[16];
    const float* gate     = (const float*)d_in[17];
    const float* ffn_g    = (const float*)d_in[18];
    const float* ffn_b    = (const float*)d_in[19];
    const float* ffn_w1   = (const float*)d_in[20];
    const float* ffn_b1   = (const float*)d_in[21];
    const float* ffn_w2   = (const float*)d_in[22];
    const float* ffn_b2   = (const float*)d_in[23];
    float* out = (float*)d_out;   // fp32 output (reference returns float32)

    // Workspace layout — 96 MiB peak
    char* ws = (char*)d_ws;
    float* resid  = (float*)(ws);                 // [0,16M)   fp32 residual
    short* lnbuf  = (short*)(ws + (16l << 20));   // [16,24M)  LN outputs (bf16)
    short* Obuf   = (short*)(ws + (24l << 20));   // [24,32M)  attn head outputs
    short* vt     = (short*)(ws + (32l << 20));   // [32,40M)  transposed V
    short* qkv    = (short*)(ws + (40l << 20));   // [40,64M)  qkv / q2+kv2; later FFN weights
    short* Sbuf   = (short*)(ws + (64l << 20));   // [64,96M)  scores / f1 chunks
    short* f1     = Sbuf;
    short* kv2    = qkv + 4194304;                // [48,49M)  CA k/v proj (256 x 2048)
    short* w_sawo = (short*)(ws + (80l << 20));   // [80,82M)  sa_wo bf16
    short* w_caq  = (short*)(ws + (82l << 20));   // [82,88M)  ca_wqkv bf16
    short* w_cawo = (short*)(ws + (88l << 20));   // [88,90M)  ca_wo bf16
    short* w_saq  = (short*)(ws + (90l << 20));   // [90,96M)  sa_wqkv bf16 (dead after qkv GEMM)
    short* w_f1   = qkv;                          // [40,56M)  ffn_w1 bf16 (after CA S2)
    short* w_f2   = (short*)(ws + (56l << 20));   // [56,64M)  ffn_w2 bf16

    const dim3 blk(256);

    // Convert attention weights fp32 -> bf16
    cvt_bf16<<<1536, blk, 0, stream>>>(sa_wqkv, w_saq, 3145728);
    cvt_bf16<<<512,  blk, 0, stream>>>(sa_wo,   w_sawo, 1048576);
    cvt_bf16<<<1536, blk, 0, stream>>>(ca_wqkv, w_caq, 3145728);
    cvt_bf16<<<512,  blk, 0, stream>>>(ca_wo,   w_cawo, 1048576);

    // residual <- x (fp32 d2d copy)
    hipMemcpyAsync(resid, x, (size_t)4194304 * 4, hipMemcpyDeviceToDevice, stream);
    // h = LN(x)
    ln_rows<<<4096, blk, 0, stream>>>(x, n1g, n1b, lnbuf);

    // qkv = h @ sa_wqkv^T + b   (4096 x 3072)
    {
        GArgs a{}; a.A = lnbuf; a.lda = 1024; a.B = w_saq; a.ldb = 1024;
        a.C = qkv; a.ldc = 3072; a.bias = sa_bqkv; a.K = 1024; a.nh = 1; a.scale = 1.f;
        gemm_bt<128, 128, 0><<<dim3(24, 32, 1), blk, 0, stream>>>(a);
    }
    transpose_v_sa<<<dim3(16, 16, 4), blk, 0, stream>>>(qkv, vt);

    // self-attention, chunked (b, half-heads): S chunk = 8 x 1024 x 1024 = 16 MiB
    for (int c = 0; c < 8; c++) {
        const int b = c >> 1, hc = c & 1;
        const long boff = (long)b * 1024 * 3072;
        {   // S = (q k^T)/8 + alibi
            GArgs a{}; a.A = qkv + boff + hc * 512; a.lda = 3072; a.sAh = 64;
            a.B = qkv + boff + 1024 + hc * 512; a.ldb = 3072; a.sBh = 64;
            a.C = Sbuf; a.ldc = 1024; a.sCh = 1048576;
            a.addm = alibi + ((long)(b * 16 + hc * 8)) * 1048576; a.ldad = 1024; a.sDh = 1048576;
            a.scale = 0.125f; a.K = 64; a.nh = 8;
            gemm_bt<128, 128, 1><<<dim3(8, 8, 8), blk, 0, stream>>>(a);
        }
        softmax1024<<<8192, blk, 0, stream>>>(Sbuf);
        {   // O = P @ V  (per head, N = HD = 64)
            GArgs a{}; a.A = Sbuf; a.lda = 1024; a.sAh = 1048576;
            a.B = vt + (long)b * 1048576 + (long)hc * 8 * 65536; a.ldb = 1024; a.sBh = 65536;
            a.C = Obuf + (long)b * 1048576 + hc * 512; a.ldc = 1024; a.sCh = 64;
            a.K = 1024; a.nh = 8; a.scale = 1.f;
            gemm_bt<64, 64, 0><<<dim3(1, 16, 8), blk, 0, stream>>>(a);
        }
    }
    {   // resid += O @ sa_wo^T + bo
        GArgs a{}; a.A = Obuf; a.lda = 1024; a.B = w_sawo; a.ldb = 1024;
        a.ldc = 1024; a.bias = sa_bo; a.resid = resid; a.scale = 1.f; a.K = 1024; a.nh = 1;
        gemm_bt<128, 128, 2><<<dim3(8, 32, 1), blk, 0, stream>>>(a);
    }

    // ---- cross attention ----
    ln_rows<<<4096, blk, 0, stream>>>(resid, ca_nq_g, ca_nq_b, lnbuf);
    {   // q2 = LN(x) @ ca_wqkv[0:1024]^T + b
        GArgs a{}; a.A = lnbuf; a.lda = 1024; a.B = w_caq; a.ldb = 1024;
        a.C = qkv; a.ldc = 1024; a.bias = ca_bqkv; a.K = 1024; a.nh = 1; a.scale = 1.f;
        gemm_bt<128, 128, 0><<<dim3(8, 32, 1), blk, 0, stream>>>(a);
    }
    ln_rows<<<256, blk, 0, stream>>>(species, ca_nkv_g, ca_nkv_b, lnbuf);
    {   // kv2 = LN(species) @ ca_wqkv[1024:3072]^T + b   (256 x 2048)
        GArgs a{}; a.A = lnbuf; a.lda = 1024; a.B = w_caq + 1024 * 1024; a.ldb = 1024;
        a.C = kv2; a.ldc = 2048; a.bias = ca_bqkv + 1024; a.K = 1024; a.nh = 1; a.scale = 1.f;
        gemm_bt<128, 128, 0><<<dim3(16, 2, 1), blk, 0, stream>>>(a);
    }
    transpose_v_ca<<<64, blk, 0, stream>>>(kv2, vt);
    {   // S2 = (q2 k2^T)/8   (per b,h: 1024 x 64)
        GArgs a{}; a.A = qkv; a.lda = 1024; a.sAb = 1048576; a.sAh = 64;
        a.B = kv2; a.ldb = 2048; a.sBb = 131072; a.sBh = 64;
        a.C = Sbuf; a.ldc = 64; a.sCb = 1048576; a.sCh = 65536;
        a.scale = 0.125f; a.K = 64; a.nh = 16;
        gemm_bt<64, 64, 1><<<dim3(1, 16, 64), blk, 0, stream>>>(a);
    }
    // qkv/kv2 now dead -> convert FFN weights into that region
    cvt_bf16<<<4096, blk, 0, stream>>>(ffn_w1, w_f1, 8388608);
    cvt_bf16<<<2048, blk, 0, stream>>>(ffn_w2, w_f2, 4194304);

    softmax64<<<16384, blk, 0, stream>>>(Sbuf);
    {   // O = P2 @ V2
        GArgs a{}; a.A = Sbuf; a.lda = 64; a.sAb = 1048576; a.sAh = 65536;
        a.B = vt; a.ldb = 64; a.sBb = 65536; a.sBh = 4096;
        a.C = Obuf; a.ldc = 1024; a.sCb = 1048576; a.sCh = 64;
        a.K = 64; a.nh = 16; a.scale = 1.f;
        gemm_bt<64, 64, 0><<<dim3(1, 16, 64), blk, 0, stream>>>(a);
    }
    {   // resid += sigmoid(gate) * (O @ ca_wo^T + bo)
        GArgs a{}; a.A = Obuf; a.lda = 1024; a.B = w_cawo; a.ldb = 1024;
        a.ldc = 1024; a.bias = ca_bo; a.resid = resid; a.gate = gate;
        a.scale = 1.f; a.K = 1024; a.nh = 1;
        gemm_bt<128, 128, 2><<<dim3(8, 32, 1), blk, 0, stream>>>(a);
    }

    // ---- FFN ----
    ln_rows<<<4096, blk, 0, stream>>>(resid, ffn_g, ffn_b, lnbuf);
    // row-chunked x2: f1 chunk = 2048 x 8192 bf16 = 32 MiB at [64,96M)
    for (int rc = 0; rc < 2; rc++) {
        const long ro = (long)rc * 2048;
        {   // f1c = LN(x)[rows] @ ffn_w1^T + b1   (2048 x 8192)
            GArgs a{}; a.A = lnbuf + ro * 1024; a.lda = 1024; a.B = w_f1; a.ldb = 1024;
            a.C = f1; a.ldc = 8192; a.bias = ffn_b1; a.K = 1024; a.nh = 1; a.scale = 1.f;
            gemm_bt<128, 128, 0><<<dim3(64, 16, 1), blk, 0, stream>>>(a);
        }
        geglu_inplace<<<4096, blk, 0, stream>>>(f1);
        {   // out[rows] = resid[rows] + g @ ffn_w2^T + b2
            GArgs a{}; a.A = f1; a.lda = 8192; a.B = w_f2; a.ldb = 4096;
            a.ldc = 1024; a.bias = ffn_b2; a.resid = resid + ro * 1024; a.outf = out + ro * 1024;
            a.scale = 1.f; a.K = 4096; a.nh = 1;
            gemm_bt<128, 128, 3><<<dim3(8, 16, 1), blk, 0, stream>>>(a);
        }
    }
}